// Round 3
// baseline (75.597 us; speedup 1.0000x reference)
//
#include <hip/hip_runtime.h>

#define NN 1000000
#define NG 20000
#define C_ 10
#define M_ 50
#define G_ 8

// Tables persist between kernels within one launch (rewritten every call).
__device__ float g_lik[M_ * G_];
__device__ float g_hst[M_ * G_];
__device__ int   g_is64;

// ---------------------------------------------------------------------------
// Kernel 0: detect input int width. x values are in [0,50): if stored int64,
// every odd int32 word is zero. Check 128 odd words (P_false = 50^-128).
// ---------------------------------------------------------------------------
__global__ __launch_bounds__(64) void k_detect(const int* __restrict__ x) {
    const int lane = threadIdx.x;
    const int v = x[2 * lane + 1] | x[128 + 2 * lane + 1];
    const unsigned long long nz = __ballot(v != 0);
    if (lane == 0) g_is64 = (nz == 0ULL) ? 1 : 0;
}

// ---------------------------------------------------------------------------
// Kernel A: build per-label tables.
//   s[c] = log sm_Pi[c,g] + log sm_B[c,m,g]  (log of numerator)
//   lik_tab[m,g] = sum_c softmax_c(s) * s ;  hst_tab[m,g] = argmax_c s (first max)
// ---------------------------------------------------------------------------
__global__ __launch_bounds__(512) void k_tables(const float* __restrict__ B,
                                                const float* __restrict__ Pi) {
    __shared__ float sZB[C_ * G_];  // logZ of softmax over M, per (c,g)
    __shared__ float sZP[G_];       // logZ of softmax over C, per g
    const int t = threadIdx.x;

    if (t < C_ * G_) {
        const int c = t >> 3, g = t & 7;
        float mx = -1e30f;
        for (int m = 0; m < M_; ++m) mx = fmaxf(mx, B[(c * M_ + m) * G_ + g]);
        float Z = 0.f;
        for (int m = 0; m < M_; ++m) Z += expf(B[(c * M_ + m) * G_ + g] - mx);
        sZB[t] = mx + logf(Z);
    } else if (t < C_ * G_ + G_) {
        const int g = t - C_ * G_;
        float mx = -1e30f;
        for (int c = 0; c < C_; ++c) mx = fmaxf(mx, Pi[c * G_ + g]);
        float Z = 0.f;
        for (int c = 0; c < C_; ++c) Z += expf(Pi[c * G_ + g] - mx);
        sZP[g] = mx + logf(Z);
    }
    __syncthreads();

    if (t < M_ * G_) {
        const int m = t >> 3, g = t & 7;
        float s[C_];
        float mx = -1e30f, bv = -1e30f;
        int bi = 0;
        for (int c = 0; c < C_; ++c) {
            const float v = (B[(c * M_ + m) * G_ + g] - sZB[c * G_ + g]) +
                            (Pi[c * G_ + g] - sZP[g]);
            s[c] = v;
            if (v > bv) { bv = v; bi = c; }  // strict > keeps FIRST max (jnp.argmax)
            mx = fmaxf(mx, v);
        }
        float Z = 0.f, W = 0.f;
        for (int c = 0; c < C_; ++c) {
            const float e = expf(s[c] - mx);
            Z += e;
            W += e * s[c];
        }
        g_lik[t] = W / Z;
        g_hst[t] = (float)bi;
    }
}

// ---------------------------------------------------------------------------
// Kernel B: h_states[n, :] = hst_tab[x[n], :]   (4 nodes per thread)
// LDS table padded to stride 9 (gcd(9,32)=1 -> banks spread, ~2-way conflicts)
// ---------------------------------------------------------------------------
__global__ __launch_bounds__(256) void k_hstates(const int* __restrict__ x,
                                                 float* __restrict__ outh) {
    __shared__ float lh[M_ * 9];
    const int t = threadIdx.x;
    for (int i = t; i < M_ * G_; i += 256)          // 400 entries, 256 threads
        lh[(i >> 3) * 9 + (i & 7)] = g_hst[i];
    __syncthreads();

    const int tid = blockIdx.x * 256 + t;
    if (tid >= NN / 4) return;

    int xs[4];
    if (g_is64) {
        const int4* p = (const int4*)x + (size_t)tid * 2;  // 4 int64s = 2 int4s
        const int4 a = p[0], b = p[1];
        xs[0] = a.x; xs[1] = a.z; xs[2] = b.x; xs[3] = b.z;
    } else {
        const int4 v = ((const int4*)x)[tid];
        xs[0] = v.x; xs[1] = v.y; xs[2] = v.z; xs[3] = v.w;
    }

    float4* op = (float4*)outh + (size_t)tid * 8;
#pragma unroll
    for (int k = 0; k < 4; ++k) {
        const int xi = xs[k];
        float4 a, b;
        a.x = lh[xi * 9 + 0]; a.y = lh[xi * 9 + 1];
        a.z = lh[xi * 9 + 2]; a.w = lh[xi * 9 + 3];
        b.x = lh[xi * 9 + 4]; b.y = lh[xi * 9 + 5];
        b.z = lh[xi * 9 + 6]; b.w = lh[xi * 9 + 7];
        op[k * 2 + 0] = a;
        op[k * 2 + 1] = b;
    }
}

// ---------------------------------------------------------------------------
// Kernel C: likelihood[g, :] = sum_{n: batch[n]==g} lik_tab[x[n], :]
// One wave per graph. batch is SORTED -> two interleaved binary searches give
// the node range; no atomics, deterministic, every output element written.
// ---------------------------------------------------------------------------
__global__ __launch_bounds__(256) void k_lik(const int* __restrict__ x,
                                             const int* __restrict__ batch,
                                             float* __restrict__ out) {
    __shared__ float ll[M_ * 9];
    const int t = threadIdx.x;
    for (int i = t; i < M_ * G_; i += 256)          // 400 entries, 256 threads
        ll[(i >> 3) * 9 + (i & 7)] = g_lik[i];
    __syncthreads();

    const int is64 = g_is64;
    const int wid = t >> 6, lane = t & 63;
    const int gid = blockIdx.x * 4 + wid;
    if (gid >= NG) return;

    // lower_bound(batch, gid) and lower_bound(batch, gid+1), interleaved (ILP 2).
    int lo0 = 0, hi0 = NN, lo1 = 0, hi1 = NN;
#pragma unroll 1
    for (int it = 0; it < 20; ++it) {  // 2^20 >= NN
        if (lo0 < hi0) {
            const int m0 = (lo0 + hi0) >> 1;
            const int b0 = is64 ? batch[2 * m0] : batch[m0];
            if (b0 < gid) lo0 = m0 + 1; else hi0 = m0;
        }
        if (lo1 < hi1) {
            const int m1 = (lo1 + hi1) >> 1;
            const int b1 = is64 ? batch[2 * m1] : batch[m1];
            if (b1 < gid + 1) lo1 = m1 + 1; else hi1 = m1;
        }
    }

    float acc[8] = {0.f, 0.f, 0.f, 0.f, 0.f, 0.f, 0.f, 0.f};
    for (int i = lo0 + lane; i < lo1; i += 64) {
        const int xi = is64 ? x[2 * i] : x[i];
#pragma unroll
        for (int g = 0; g < 8; ++g) acc[g] += ll[xi * 9 + g];
    }
#pragma unroll
    for (int d = 1; d < 64; d <<= 1) {
#pragma unroll
        for (int g = 0; g < 8; ++g) acc[g] += __shfl_xor(acc[g], d, 64);
    }
    if (lane == 0) {
        float4 a = {acc[0], acc[1], acc[2], acc[3]};
        float4 b = {acc[4], acc[5], acc[6], acc[7]};
        ((float4*)out)[gid * 2 + 0] = a;
        ((float4*)out)[gid * 2 + 1] = b;
    }
}

// ---------------------------------------------------------------------------
extern "C" void kernel_launch(void* const* d_in, const int* in_sizes, int n_in,
                              void* d_out, int out_size, void* d_ws, size_t ws_size,
                              hipStream_t stream) {
    const int*   x     = (const int*)d_in[0];
    const int*   batch = (const int*)d_in[1];
    const float* B     = (const float*)d_in[2];
    const float* Pi    = (const float*)d_in[3];
    float* out  = (float*)d_out;             // likelihood [NG, G_] first
    float* outh = (float*)d_out + NG * G_;   // then h_states [NN, G_]

    k_detect<<<1, 64, 0, stream>>>(x);
    k_tables<<<1, 512, 0, stream>>>(B, Pi);
    k_hstates<<<(NN / 4 + 255) / 256, 256, 0, stream>>>(x, outh);
    k_lik<<<NG / 4, 256, 0, stream>>>(x, batch, out);
}

// Round 4
// 45.418 us; speedup vs baseline: 1.6645x; 1.6645x over previous
//
#include <hip/hip_runtime.h>

#define NN 1000000
#define NG 20000
#define C_ 10
#define M_ 50
#define G_ 8

// Tables persist between kernels within one launch (rewritten every call).
__device__ float g_lik[M_ * G_];
__device__ float g_hst[M_ * G_];
__device__ int   g_is64;

// ---------------------------------------------------------------------------
// Kernel A (1 block, 512 threads): int-width detect (wave 7) + per-label tables.
//   s[c] = log sm_Pi[c,g] + log sm_B[c,m,g]  (log of numerator)
//   lik_tab[m,g] = sum_c softmax_c(s) * s ;  hst_tab[m,g] = argmax_c s (first max)
// ---------------------------------------------------------------------------
__global__ __launch_bounds__(512) void k_tables(const float* __restrict__ B,
                                                const float* __restrict__ Pi,
                                                const int* __restrict__ x) {
    __shared__ float sZB[C_ * G_];  // logZ of softmax over M, per (c,g)
    __shared__ float sZP[G_];       // logZ of softmax over C, per g
    const int t = threadIdx.x;

    if (t >= 448) {  // wave 7: detect int64 inputs (x in [0,50) -> odd words zero)
        const int lane = t - 448;
        const int v = x[2 * lane + 1] | x[128 + 2 * lane + 1];
        const unsigned long long nz = __ballot(v != 0);
        if (lane == 0) g_is64 = (nz == 0ULL) ? 1 : 0;  // P_false = 50^-128
    }

    if (t < C_ * G_) {
        const int c = t >> 3, g = t & 7;
        float mx = -1e30f;
        for (int m = 0; m < M_; ++m) mx = fmaxf(mx, B[(c * M_ + m) * G_ + g]);
        float Z = 0.f;
        for (int m = 0; m < M_; ++m) Z += expf(B[(c * M_ + m) * G_ + g] - mx);
        sZB[t] = mx + logf(Z);
    } else if (t < C_ * G_ + G_) {
        const int g = t - C_ * G_;
        float mx = -1e30f;
        for (int c = 0; c < C_; ++c) mx = fmaxf(mx, Pi[c * G_ + g]);
        float Z = 0.f;
        for (int c = 0; c < C_; ++c) Z += expf(Pi[c * G_ + g] - mx);
        sZP[g] = mx + logf(Z);
    }
    __syncthreads();

    if (t < M_ * G_) {
        const int m = t >> 3, g = t & 7;
        float s[C_];
        float mx = -1e30f, bv = -1e30f;
        int bi = 0;
        for (int c = 0; c < C_; ++c) {
            const float v = (B[(c * M_ + m) * G_ + g] - sZB[c * G_ + g]) +
                            (Pi[c * G_ + g] - sZP[g]);
            s[c] = v;
            if (v > bv) { bv = v; bi = c; }  // strict > keeps FIRST max (jnp.argmax)
            mx = fmaxf(mx, v);
        }
        float Z = 0.f, W = 0.f;
        for (int c = 0; c < C_; ++c) {
            const float e = expf(s[c] - mx);
            Z += e;
            W += e * s[c];
        }
        g_lik[t] = W / Z;
        g_hst[t] = (float)bi;
    }
}

// ---------------------------------------------------------------------------
// Kernel B: fused node-parallel pass (4 nodes/thread):
//   1) h_states[n,:] = hst_tab[x[n],:]
//   2) boundary scatter: starts[g] = lower_bound(batch, g)  (batch is sorted;
//      each entry written exactly once; empties + tail covered) -> no binary
//      search needed downstream. Deterministic, no atomics.
// ---------------------------------------------------------------------------
__global__ __launch_bounds__(256) void k_scan(const int* __restrict__ x,
                                              const int* __restrict__ batch,
                                              float* __restrict__ outh,
                                              int* __restrict__ starts) {
    __shared__ float lh[M_ * 9];  // stride 9: gcd(9,32)=1 -> ~2-way conflicts (free)
    const int t = threadIdx.x;
    for (int i = t; i < M_ * G_; i += 256)
        lh[(i >> 3) * 9 + (i & 7)] = g_hst[i];
    __syncthreads();

    const int tid = blockIdx.x * 256 + t;
    if (tid >= NN / 4) return;
    const int is64 = g_is64;

    int xs[4], bs[4], prev;
    if (is64) {
        const int4* p = (const int4*)x + (size_t)tid * 2;  // 4 int64 = 2 int4
        const int4 a = p[0], b = p[1];
        xs[0] = a.x; xs[1] = a.z; xs[2] = b.x; xs[3] = b.z;
        const int4* q = (const int4*)batch + (size_t)tid * 2;
        const int4 c = q[0], d = q[1];
        bs[0] = c.x; bs[1] = c.z; bs[2] = d.x; bs[3] = d.z;
        prev = (tid == 0) ? -1 : batch[8 * tid - 2];  // low word of batch[4t-1]
    } else {
        const int4 v = ((const int4*)x)[tid];
        xs[0] = v.x; xs[1] = v.y; xs[2] = v.z; xs[3] = v.w;
        const int4 w = ((const int4*)batch)[tid];
        bs[0] = w.x; bs[1] = w.y; bs[2] = w.z; bs[3] = w.w;
        prev = (tid == 0) ? -1 : batch[4 * tid - 1];
    }

    float4* op = (float4*)outh + (size_t)tid * 8;
#pragma unroll
    for (int k = 0; k < 4; ++k) {
        const int xi = xs[k];
        float4 a, b;
        a.x = lh[xi * 9 + 0]; a.y = lh[xi * 9 + 1];
        a.z = lh[xi * 9 + 2]; a.w = lh[xi * 9 + 3];
        b.x = lh[xi * 9 + 4]; b.y = lh[xi * 9 + 5];
        b.z = lh[xi * 9 + 6]; b.w = lh[xi * 9 + 7];
        op[k * 2 + 0] = a;
        op[k * 2 + 1] = b;
    }

#pragma unroll
    for (int k = 0; k < 4; ++k) {
        const int n = 4 * tid + k;
        for (int g = prev + 1; g <= bs[k]; ++g) starts[g] = n;
        prev = bs[k];
    }
    if (tid == NN / 4 - 1) {
        for (int g = prev + 1; g <= NG; ++g) starts[g] = NN;
    }
}

// ---------------------------------------------------------------------------
// Kernel C: likelihood[g,:] = sum_{n in [starts[g],starts[g+1])} lik_tab[x[n],:]
// One wave per graph; lane = (node-slot ns = lane>>3, gen r = lane&7).
// ~ceil(len/8) iterations, then 3-step shfl_xor reduce over node slots.
// ---------------------------------------------------------------------------
__global__ __launch_bounds__(256) void k_lik(const int* __restrict__ x,
                                             const int* __restrict__ starts,
                                             float* __restrict__ out) {
    __shared__ float ll[M_ * 9];
    const int t = threadIdx.x;
    for (int i = t; i < M_ * G_; i += 256)
        ll[(i >> 3) * 9 + (i & 7)] = g_lik[i];
    __syncthreads();

    const int is64 = g_is64;
    const int wid = t >> 6, lane = t & 63;
    const int gid = blockIdx.x * 4 + wid;  // grid = NG/4 exactly
    const int ns = lane >> 3, r = lane & 7;

    const int lo = starts[gid], hi = starts[gid + 1];
    float acc = 0.f;
    for (int i = lo + ns; i < hi; i += 8) {
        const int xi = is64 ? x[2 * i] : x[i];
        acc += ll[xi * 9 + r];
    }
    acc += __shfl_xor(acc, 8, 64);
    acc += __shfl_xor(acc, 16, 64);
    acc += __shfl_xor(acc, 32, 64);
    if (lane < 8) out[(size_t)gid * 8 + lane] = acc;
}

// ---------------------------------------------------------------------------
extern "C" void kernel_launch(void* const* d_in, const int* in_sizes, int n_in,
                              void* d_out, int out_size, void* d_ws, size_t ws_size,
                              hipStream_t stream) {
    const int*   x     = (const int*)d_in[0];
    const int*   batch = (const int*)d_in[1];
    const float* B     = (const float*)d_in[2];
    const float* Pi    = (const float*)d_in[3];
    float* out  = (float*)d_out;             // likelihood [NG, G_] first
    float* outh = (float*)d_out + NG * G_;   // then h_states [NN, G_]
    int* starts = (int*)d_ws;                // NG+1 ints, fully rewritten each call

    k_tables<<<1, 512, 0, stream>>>(B, Pi, x);
    k_scan<<<(NN / 4 + 255) / 256, 256, 0, stream>>>(x, batch, outh, starts);
    k_lik<<<NG / 4, 256, 0, stream>>>(x, starts, out);
}

// Round 5
// 30.256 us; speedup vs baseline: 2.4986x; 1.5011x over previous
//
#include <hip/hip_runtime.h>

#define NN 1000000
#define NG 20000
#define C_ 10
#define M_ 50
#define G_ 8

// Tables persist between kernels within one launch (rewritten every call).
__device__ float g_lik[M_ * G_];
__device__ float g_hst[M_ * G_];
__device__ int   g_is64;

// ---------------------------------------------------------------------------
// Kernel A (1 block, 512 threads): int-width detect (wave 7) + per-label tables.
// B (4000 f32) and Pi (80 f32) staged to LDS with coalesced float4 loads first;
// all softmax math then runs on LDS instead of scattered L2-cold scalar loads.
//   s[c] = log sm_Pi[c,g] + log sm_B[c,m,g]
//   lik_tab[m,g] = sum_c softmax_c(s)*s ; hst_tab[m,g] = argmax_c s (first max)
// ---------------------------------------------------------------------------
__global__ __launch_bounds__(512) void k_tables(const float* __restrict__ B,
                                                const float* __restrict__ Pi,
                                                const int* __restrict__ x) {
    __shared__ float sB[C_ * M_ * G_];  // 4000
    __shared__ float sP[C_ * G_];       // 80
    __shared__ float sZB[C_ * G_];      // logZ over M per (c,g)
    __shared__ float sZP[G_];           // logZ over C per g
    const int t = threadIdx.x;

    if (t >= 448) {  // wave 7: detect int64 inputs (x in [0,50) -> odd words zero)
        const int lane = t - 448;
        const int v = x[2 * lane + 1] | x[128 + 2 * lane + 1];
        const unsigned long long nz = __ballot(v != 0);
        if (lane == 0) g_is64 = (nz == 0ULL) ? 1 : 0;  // P_false = 50^-128
    }
    for (int i = t; i < C_ * M_ * G_ / 4; i += 512)
        ((float4*)sB)[i] = ((const float4*)B)[i];
    if (t < C_ * G_ / 4) ((float4*)sP)[t] = ((const float4*)Pi)[t];
    __syncthreads();

    if (t < C_ * G_) {
        const int c = t >> 3, g = t & 7;
        float mx = -1e30f;
        for (int m = 0; m < M_; ++m) mx = fmaxf(mx, sB[(c * M_ + m) * G_ + g]);
        float Z = 0.f;
        for (int m = 0; m < M_; ++m) Z += expf(sB[(c * M_ + m) * G_ + g] - mx);
        sZB[t] = mx + logf(Z);
    } else if (t < C_ * G_ + G_) {
        const int g = t - C_ * G_;
        float mx = -1e30f;
        for (int c = 0; c < C_; ++c) mx = fmaxf(mx, sP[c * G_ + g]);
        float Z = 0.f;
        for (int c = 0; c < C_; ++c) Z += expf(sP[c * G_ + g] - mx);
        sZP[g] = mx + logf(Z);
    }
    __syncthreads();

    if (t < M_ * G_) {
        const int m = t >> 3, g = t & 7;
        float s[C_];
        float mx = -1e30f, bv = -1e30f;
        int bi = 0;
        for (int c = 0; c < C_; ++c) {
            const float v = (sB[(c * M_ + m) * G_ + g] - sZB[c * G_ + g]) +
                            (sP[c * G_ + g] - sZP[g]);
            s[c] = v;
            if (v > bv) { bv = v; bi = c; }  // strict > keeps FIRST max (jnp.argmax)
            mx = fmaxf(mx, v);
        }
        float Z = 0.f, W = 0.f;
        for (int c = 0; c < C_; ++c) {
            const float e = expf(s[c] - mx);
            Z += e;
            W += e * s[c];
        }
        g_lik[t] = W / Z;
        g_hst[t] = (float)bi;
    }
}

// ---------------------------------------------------------------------------
// Kernel B: 1024 nodes/block. Stage x/batch to LDS (coalesced int4), then:
//   1) h_states[n,:] = hst_tab[x[n],:] with FULLY COALESCED float4 stores
//      (out4[idx], idx = k*256+t: consecutive lanes -> consecutive 16B).
//   2) boundary scatter: starts[g] = lower_bound(batch, g). Each entry written
//      exactly once (batch sorted); empties + tail covered; deterministic.
// ---------------------------------------------------------------------------
__global__ __launch_bounds__(256) void k_scan(const int* __restrict__ x,
                                              const int* __restrict__ batch,
                                              float* __restrict__ outh,
                                              int* __restrict__ starts) {
    __shared__ float lh[M_ * 9];   // stride 9: gcd(9,32)=1 -> ~2-way conflicts (free)
    __shared__ int sx[1024];
    __shared__ int sb[1025];       // sb[0] = batch[base-1] (or -1); sb[1+i] = batch[base+i]
    const int t = threadIdx.x;
    const int base = blockIdx.x * 1024;
    const int limit = (NN - base < 1024) ? (NN - base) : 1024;  // multiple of 4
    const int is64 = g_is64;

    for (int i = t; i < M_ * G_; i += 256)
        lh[(i >> 3) * 9 + (i & 7)] = g_hst[i];

    if (is64) {
        const int4* xq = (const int4*)x + (base >> 1);      // 2 int64 per int4
        const int4* bq = (const int4*)batch + (base >> 1);
        for (int i = t; i < (limit >> 1); i += 256) {
            const int4 v = xq[i];
            sx[2 * i] = v.x; sx[2 * i + 1] = v.z;
            const int4 w = bq[i];
            sb[1 + 2 * i] = w.x; sb[1 + 2 * i + 1] = w.z;
        }
        if (t == 0) sb[0] = (base == 0) ? -1 : batch[2 * (base - 1)];
    } else {
        const int4* xq = (const int4*)x + (base >> 2);
        const int4* bq = (const int4*)batch + (base >> 2);
        for (int i = t; i < (limit >> 2); i += 256) {
            const int4 v = xq[i];
            sx[4 * i] = v.x; sx[4 * i + 1] = v.y; sx[4 * i + 2] = v.z; sx[4 * i + 3] = v.w;
            const int4 w = bq[i];
            sb[1 + 4 * i] = w.x; sb[2 + 4 * i] = w.y; sb[3 + 4 * i] = w.z; sb[4 + 4 * i] = w.w;
        }
        if (t == 0) sb[0] = (base == 0) ? -1 : batch[base - 1];
    }
    __syncthreads();

    // ---- h_states: coalesced. float4 idx -> node idx/2, half idx&1.
    float4* op = (float4*)outh + (size_t)base * 2;
    const int nf4 = limit * 2;
    for (int idx = t; idx < nf4; idx += 256) {
        const int xi = sx[idx >> 1];
        const int o = xi * 9 + (idx & 1) * 4;
        float4 v;
        v.x = lh[o]; v.y = lh[o + 1]; v.z = lh[o + 2]; v.w = lh[o + 3];
        op[idx] = v;
    }

    // ---- boundary scatter (4 nodes per thread, from LDS)
    if (4 * t < limit) {
        int prev = sb[4 * t];
#pragma unroll
        for (int k = 0; k < 4; ++k) {
            const int b = sb[1 + 4 * t + k];
            const int n = base + 4 * t + k;
            for (int g = prev + 1; g <= b; ++g) starts[g] = n;
            prev = b;
        }
        if (base + limit == NN && t == ((limit - 1) >> 2)) {  // owner of last node
            for (int g = prev + 1; g <= NG; ++g) starts[g] = NN;
        }
    }
}

// ---------------------------------------------------------------------------
// Kernel C: likelihood[g,:] = sum_{n in [starts[g],starts[g+1])} lik_tab[x[n],:]
// One wave per graph; lane = (node-slot ns = lane>>3, gen r = lane&7).
// ~ceil(len/8) iterations, then 3-step shfl_xor reduce over node slots.
// ---------------------------------------------------------------------------
__global__ __launch_bounds__(256) void k_lik(const int* __restrict__ x,
                                             const int* __restrict__ starts,
                                             float* __restrict__ out) {
    __shared__ float ll[M_ * 9];
    const int t = threadIdx.x;
    for (int i = t; i < M_ * G_; i += 256)
        ll[(i >> 3) * 9 + (i & 7)] = g_lik[i];
    __syncthreads();

    const int is64 = g_is64;
    const int wid = t >> 6, lane = t & 63;
    const int gid = blockIdx.x * 4 + wid;  // grid = NG/4 exactly
    const int ns = lane >> 3, r = lane & 7;

    const int lo = starts[gid], hi = starts[gid + 1];
    float acc = 0.f;
    for (int i = lo + ns; i < hi; i += 8) {
        const int xi = is64 ? x[2 * i] : x[i];
        acc += ll[xi * 9 + r];
    }
    acc += __shfl_xor(acc, 8, 64);
    acc += __shfl_xor(acc, 16, 64);
    acc += __shfl_xor(acc, 32, 64);
    if (lane < 8) out[(size_t)gid * 8 + lane] = acc;
}

// ---------------------------------------------------------------------------
extern "C" void kernel_launch(void* const* d_in, const int* in_sizes, int n_in,
                              void* d_out, int out_size, void* d_ws, size_t ws_size,
                              hipStream_t stream) {
    const int*   x     = (const int*)d_in[0];
    const int*   batch = (const int*)d_in[1];
    const float* B     = (const float*)d_in[2];
    const float* Pi    = (const float*)d_in[3];
    float* out  = (float*)d_out;             // likelihood [NG, G_] first
    float* outh = (float*)d_out + NG * G_;   // then h_states [NN, G_]
    int* starts = (int*)d_ws;                // NG+1 ints, fully rewritten each call

    k_tables<<<1, 512, 0, stream>>>(B, Pi, x);
    k_scan<<<(NN + 1023) / 1024, 256, 0, stream>>>(x, batch, outh, starts);
    k_lik<<<NG / 4, 256, 0, stream>>>(x, starts, out);
}

// Round 6
// 27.450 us; speedup vs baseline: 2.7540x; 1.1022x over previous
//
#include <hip/hip_runtime.h>

#define NN 1000000
#define NG 20000
#define C_ 10
#define M_ 50
#define G_ 8

// Written by k_scan blocks 0..49 (one m-row each), read by k_lik next kernel.
__device__ float g_lik[M_ * G_];

// ---------------------------------------------------------------------------
// K1: per-block: detect int width + stage B + sZB logsumexp (waves 0-1,
// overlapped with x/batch staging on waves 2-3) + hst argmax table +
// coalesced h_states writes + boundary scatter. Blocks 0..49 also publish
// g_lik row m=blockIdx (needs sZP too; sZP is constant in c so it cancels
// out of the argmax and is NOT needed for h_states).
// ---------------------------------------------------------------------------
__global__ __launch_bounds__(256) void k_scan(const float* __restrict__ B,
                                              const float* __restrict__ Pi,
                                              const int* __restrict__ x,
                                              const int* __restrict__ batch,
                                              float* __restrict__ outh,
                                              int* __restrict__ starts) {
    __shared__ float sB[C_ * M_ * G_];   // 4000 f32
    __shared__ float sPi[C_ * G_];       // only used by blocks < 50
    __shared__ float sZB[C_ * G_];       // logZ over M per (c,g)
    __shared__ float sZP[G_];            // logZ over C per g (blocks < 50)
    __shared__ float lh[M_ * 9];         // hst table, stride 9 (2-way conflicts = free)
    __shared__ int   sx[1024];
    __shared__ int   sb[1025];           // sb[0] = batch[base-1] or -1
    __shared__ int   s_is64;

    const int t = threadIdx.x;
    const int bid = blockIdx.x;
    const int base = bid * 1024;
    const int limit = (NN - base < 1024) ? (NN - base) : 1024;  // multiple of 4

    // ---- phase A: detect (wave 0) + Pi stage (blocks<50) + B stage (all)
    if (t < 64) {
        // x in [0,50): if int64, every odd int32 word is zero. P_false = 50^-128.
        const int v = x[2 * t + 1] | x[128 + 2 * t + 1];
        const unsigned long long nz = __ballot(v != 0);
        if (t == 0) s_is64 = (nz == 0ULL) ? 1 : 0;
    } else if (t < 144 && bid < 50) {
        sPi[t - 64] = Pi[t - 64];
    }
    for (int i = t; i < C_ * M_ * G_ / 4; i += 256)
        ((float4*)sB)[i] = ((const float4*)B)[i];
    __syncthreads();
    const int is64 = s_is64;

    // ---- phase B: sZB (t<80) || sZP (t 80..87, blocks<50) || x/batch stage (t>=128)
    if (t < 80) {
        const int c = t >> 3, g = t & 7;
        float mx = -1e30f;
        for (int m = 0; m < M_; ++m) mx = fmaxf(mx, sB[(c * M_ + m) * G_ + g]);
        float Z = 0.f;
        for (int m = 0; m < M_; ++m) Z += __expf(sB[(c * M_ + m) * G_ + g] - mx);
        sZB[t] = mx + __logf(Z);
    } else if (t < 88 && bid < 50) {
        const int g = t - 80;
        float mx = -1e30f;
        for (int c = 0; c < C_; ++c) mx = fmaxf(mx, sPi[c * G_ + g]);
        float Z = 0.f;
        for (int c = 0; c < C_; ++c) Z += __expf(sPi[c * G_ + g] - mx);
        sZP[g] = mx + __logf(Z);
    } else if (t >= 128) {
        if (is64) {
            const int4* xq = (const int4*)x + (base >> 1);      // 2 int64 per int4
            const int4* bq = (const int4*)batch + (base >> 1);
            for (int i = t - 128; i < (limit >> 1); i += 128) {
                const int4 v = xq[i];
                sx[2 * i] = v.x; sx[2 * i + 1] = v.z;
                const int4 w = bq[i];
                sb[1 + 2 * i] = w.x; sb[2 + 2 * i] = w.z;
            }
            if (t == 128) sb[0] = (base == 0) ? -1 : batch[2 * (base - 1)];
        } else {
            const int4* xq = (const int4*)x + (base >> 2);
            const int4* bq = (const int4*)batch + (base >> 2);
            for (int i = t - 128; i < (limit >> 2); i += 128) {
                const int4 v = xq[i];
                sx[4 * i] = v.x; sx[4 * i + 1] = v.y; sx[4 * i + 2] = v.z; sx[4 * i + 3] = v.w;
                const int4 w = bq[i];
                sb[1 + 4 * i] = w.x; sb[2 + 4 * i] = w.y; sb[3 + 4 * i] = w.z; sb[4 + 4 * i] = w.w;
            }
            if (t == 128) sb[0] = (base == 0) ? -1 : batch[base - 1];
        }
    }
    __syncthreads();

    // ---- phase C: hst argmax table + boundary scatter + (bid<50) lik row publish
    for (int e = t; e < M_ * G_; e += 256) {
        const int m = e >> 3, g = e & 7;
        float bv = -1e30f;
        int bi = 0;
        for (int c = 0; c < C_; ++c) {
            const float v = sB[(c * M_ + m) * G_ + g] - sZB[c * G_ + g];
            if (v > bv) { bv = v; bi = c; }  // strict > keeps FIRST max (jnp.argmax)
        }
        lh[m * 9 + g] = (float)bi;
    }
    if (bid < 50 && t < 8) {
        const int m = bid, g = t;
        float s[C_];
        float mx = -1e30f;
        for (int c = 0; c < C_; ++c) {
            const float v = (sB[(c * M_ + m) * G_ + g] - sZB[c * G_ + g]) +
                            (sPi[c * G_ + g] - sZP[g]);
            s[c] = v;
            mx = fmaxf(mx, v);
        }
        float Z = 0.f, W = 0.f;
        for (int c = 0; c < C_; ++c) {
            const float e = __expf(s[c] - mx);
            Z += e;
            W += e * s[c];
        }
        g_lik[m * 8 + g] = W / Z;
    }
    if (4 * t < limit) {  // starts[g] = lower_bound(batch, g); each written once
        int prev = sb[4 * t];
#pragma unroll
        for (int k = 0; k < 4; ++k) {
            const int b = sb[1 + 4 * t + k];
            const int n = base + 4 * t + k;
            for (int g = prev + 1; g <= b; ++g) starts[g] = n;
            prev = b;
        }
        if (base + limit == NN && t == ((limit - 1) >> 2))  // owner of last node
            for (int g = prev + 1; g <= NG; ++g) starts[g] = NN;
    }
    __syncthreads();

    // ---- phase D: h_states, fully coalesced float4 stores
    float4* op = (float4*)outh + (size_t)base * 2;
    const int nf4 = limit * 2;
    for (int idx = t; idx < nf4; idx += 256) {
        const int xi = sx[idx >> 1];
        const int o = xi * 9 + (idx & 1) * 4;
        float4 v;
        v.x = lh[o]; v.y = lh[o + 1]; v.z = lh[o + 2]; v.w = lh[o + 3];
        op[idx] = v;
    }
}

// ---------------------------------------------------------------------------
// K2: likelihood[g,:] = sum_{n in [starts[g],starts[g+1])} g_lik[x[n],:]
// One wave per graph; lane = (node-slot ns=lane>>3, gen r=lane&7). Table read
// straight from global (1.6 KB, L1-resident; lanes r=0..7 -> 32B segments).
// ---------------------------------------------------------------------------
__global__ __launch_bounds__(256) void k_lik(const int* __restrict__ x,
                                             const int* __restrict__ starts,
                                             float* __restrict__ out) {
    __shared__ int s_is64;
    const int t = threadIdx.x;
    if (t < 64) {
        const int v = x[2 * t + 1] | x[128 + 2 * t + 1];
        const unsigned long long nz = __ballot(v != 0);
        if (t == 0) s_is64 = (nz == 0ULL) ? 1 : 0;
    }
    __syncthreads();
    const int is64 = s_is64;

    const int wid = t >> 6, lane = t & 63;
    const int gid = blockIdx.x * 4 + wid;  // grid = NG/4 exactly
    const int ns = lane >> 3, r = lane & 7;

    const int lo = starts[gid], hi = starts[gid + 1];
    float acc = 0.f;
    for (int i = lo + ns; i < hi; i += 8) {
        const int xi = is64 ? x[2 * i] : x[i];
        acc += g_lik[xi * 8 + r];
    }
    acc += __shfl_xor(acc, 8, 64);
    acc += __shfl_xor(acc, 16, 64);
    acc += __shfl_xor(acc, 32, 64);
    if (lane < 8) out[(size_t)gid * 8 + lane] = acc;
}

// ---------------------------------------------------------------------------
extern "C" void kernel_launch(void* const* d_in, const int* in_sizes, int n_in,
                              void* d_out, int out_size, void* d_ws, size_t ws_size,
                              hipStream_t stream) {
    const int*   x     = (const int*)d_in[0];
    const int*   batch = (const int*)d_in[1];
    const float* B     = (const float*)d_in[2];
    const float* Pi    = (const float*)d_in[3];
    float* out  = (float*)d_out;             // likelihood [NG, G_] first
    float* outh = (float*)d_out + NG * G_;   // then h_states [NN, G_]
    int* starts = (int*)d_ws;                // NG+1 ints, fully rewritten each call

    k_scan<<<(NN + 1023) / 1024, 256, 0, stream>>>(B, Pi, x, batch, outh, starts);
    k_lik<<<NG / 4, 256, 0, stream>>>(x, starts, out);
}

// Round 7
// 26.308 us; speedup vs baseline: 2.8736x; 1.0434x over previous
//
#include <hip/hip_runtime.h>

#define NN 1000000
#define NG 20000
#define C_ 10
#define M_ 50
#define G_ 8

// ---------------------------------------------------------------------------
// Single fused kernel. Per block of 1024 nodes:
//  A: detect int width | stage Pi | stage B (coalesced f4)
//  B: sZB logsumexp (t<80) | sZP (t<88) | stage x/batch -> LDS (t>=128)
//  C: lik+hst tables (400 entries; s_c = (logB-sZB)+(logPi-sZP); lik = sum
//     softmax(s)*s, hst = argmax_c s, strict > = first max like jnp.argmax)
//     + segment-head detection (batch sorted -> 1 segment per graph per block)
//  D: coalesced h_states float4 stores + per-segment gather/reduce +
//     atomicAdd(out). Graph spans <=2 blocks -> <=2 float contributions ->
//     commutative -> bit-deterministic. Empty graphs = memset zero.
// ---------------------------------------------------------------------------
__global__ __launch_bounds__(256) void k_fused(const float* __restrict__ B,
                                               const float* __restrict__ Pi,
                                               const int* __restrict__ x,
                                               const int* __restrict__ batch,
                                               float* __restrict__ out,
                                               float* __restrict__ outh) {
    __shared__ float sB[C_ * M_ * G_];   // 4000 f32
    __shared__ float sPi[C_ * G_];
    __shared__ float sZB[C_ * G_];       // logZ over M per (c,g)
    __shared__ float sZP[G_];            // logZ over C per g
    __shared__ float lik[M_ * 9];        // stride 9: gcd(9,32)=1, ~2-way conflicts
    __shared__ float hst[M_ * 9];
    __shared__ int   sx[1024];
    __shared__ int   sb[1025];           // sb[0] = batch[base-1] or -1
    __shared__ int   heads[1025];        // local start index of each segment
    __shared__ int   hcnt;
    __shared__ int   s_is64;

    const int t = threadIdx.x;
    const int base = blockIdx.x * 1024;
    const int limit = (NN - base < 1024) ? (NN - base) : 1024;  // multiple of 4

    // ---- phase A
    if (t < 64) {
        // x in [0,50): if int64, every odd int32 word is zero. P_false = 50^-128.
        const int v = x[2 * t + 1] | x[128 + 2 * t + 1];
        const unsigned long long nz = __ballot(v != 0);
        if (t == 0) s_is64 = (nz == 0ULL) ? 1 : 0;
    } else if (t < 144) {
        sPi[t - 64] = Pi[t - 64];
    }
    if (t == 255) hcnt = 0;
    for (int i = t; i < C_ * M_ * G_ / 4; i += 256)
        ((float4*)sB)[i] = ((const float4*)B)[i];
    __syncthreads();
    const int is64 = s_is64;

    // ---- phase B: logsumexps || x/batch staging (latency overlap)
    if (t < 80) {
        const int c = t >> 3, g = t & 7;
        float mx = -1e30f;
        for (int m = 0; m < M_; ++m) mx = fmaxf(mx, sB[(c * M_ + m) * G_ + g]);
        float Z = 0.f;
        for (int m = 0; m < M_; ++m) Z += __expf(sB[(c * M_ + m) * G_ + g] - mx);
        sZB[t] = mx + __logf(Z);
    } else if (t < 88) {
        const int g = t - 80;
        float mx = -1e30f;
        for (int c = 0; c < C_; ++c) mx = fmaxf(mx, sPi[c * G_ + g]);
        float Z = 0.f;
        for (int c = 0; c < C_; ++c) Z += __expf(sPi[c * G_ + g] - mx);
        sZP[g] = mx + __logf(Z);
    } else if (t >= 128) {
        if (is64) {
            const int4* xq = (const int4*)x + (base >> 1);      // 2 int64 per int4
            const int4* bq = (const int4*)batch + (base >> 1);
            for (int i = t - 128; i < (limit >> 1); i += 128) {
                const int4 v = xq[i];
                sx[2 * i] = v.x; sx[2 * i + 1] = v.z;
                const int4 w = bq[i];
                sb[1 + 2 * i] = w.x; sb[2 + 2 * i] = w.z;
            }
            if (t == 128) sb[0] = (base == 0) ? -1 : batch[2 * (base - 1)];
        } else {
            const int4* xq = (const int4*)x + (base >> 2);
            const int4* bq = (const int4*)batch + (base >> 2);
            for (int i = t - 128; i < (limit >> 2); i += 128) {
                const int4 v = xq[i];
                sx[4 * i] = v.x; sx[4 * i + 1] = v.y; sx[4 * i + 2] = v.z; sx[4 * i + 3] = v.w;
                const int4 w = bq[i];
                sb[1 + 4 * i] = w.x; sb[2 + 4 * i] = w.y; sb[3 + 4 * i] = w.z; sb[4 + 4 * i] = w.w;
            }
            if (t == 128) sb[0] = (base == 0) ? -1 : batch[base - 1];
        }
    }
    __syncthreads();

    // ---- phase C: tables + segment heads
    for (int e = t; e < M_ * G_; e += 256) {
        const int m = e >> 3, g = e & 7;
        float s[C_];
        float mx = -1e30f, bv = -1e30f;
        int bi = 0;
        for (int c = 0; c < C_; ++c) {
            const float v = (sB[(c * M_ + m) * G_ + g] - sZB[c * G_ + g]) +
                            (sPi[c * G_ + g] - sZP[g]);   // FULL s_c incl. sPi term
            s[c] = v;
            if (v > bv) { bv = v; bi = c; }  // strict > keeps FIRST max
            mx = fmaxf(mx, v);
        }
        float Z = 0.f, W = 0.f;
        for (int c = 0; c < C_; ++c) {
            const float ee = __expf(s[c] - mx);
            Z += ee;
            W += ee * s[c];
        }
        lik[m * 9 + g] = W / Z;
        hst[m * 9 + g] = (float)bi;
    }
    if (4 * t < limit) {
#pragma unroll
        for (int k = 0; k < 4; ++k) {
            const int i = 4 * t + k;
            // head iff first local node (covers left-straddle) or batch changes
            if (i == 0 || sb[1 + i] != sb[i])
                heads[atomicAdd(&hcnt, 1)] = i;
        }
    }
    __syncthreads();

    // ---- phase D1: h_states, fully coalesced float4 stores
    float4* op = (float4*)outh + (size_t)base * 2;
    const int nf4 = limit * 2;
    for (int idx = t; idx < nf4; idx += 256) {
        const int xi = sx[idx >> 1];
        const int o = xi * 9 + (idx & 1) * 4;
        float4 v;
        v.x = hst[o]; v.y = hst[o + 1]; v.z = hst[o + 2]; v.w = hst[o + 3];
        op[idx] = v;
    }

    // ---- phase D2: per-segment likelihood sums
    const int wid = t >> 6, lane = t & 63;
    const int ns = lane >> 3, r = lane & 7;
    const int H = hcnt;
    for (int j = wid; j < H; j += 4) {
        const int s = heads[j];
        const int g = sb[1 + s];
        // ballot-scan for segment end (1 round for typical ~50-node graphs)
        int e = limit;
        for (int bse = s; bse < limit; bse += 64) {
            const int ii = bse + lane;
            const int val = (ii < limit) ? sb[1 + ii] : (g + 1);
            const unsigned long long diff = __ballot(val != g);
            if (diff) { e = bse + __builtin_ctzll(diff); break; }
        }
        float acc = 0.f;
        for (int i = s + ns; i < e; i += 8)
            acc += lik[sx[i] * 9 + r];
        acc += __shfl_xor(acc, 8, 64);
        acc += __shfl_xor(acc, 16, 64);
        acc += __shfl_xor(acc, 32, 64);
        if (lane < 8) atomicAdd(&out[(size_t)g * 8 + lane], acc);
    }
}

// ---------------------------------------------------------------------------
extern "C" void kernel_launch(void* const* d_in, const int* in_sizes, int n_in,
                              void* d_out, int out_size, void* d_ws, size_t ws_size,
                              hipStream_t stream) {
    const int*   x     = (const int*)d_in[0];
    const int*   batch = (const int*)d_in[1];
    const float* B     = (const float*)d_in[2];
    const float* Pi    = (const float*)d_in[3];
    float* out  = (float*)d_out;             // likelihood [NG, G_] first
    float* outh = (float*)d_out + NG * G_;   // then h_states [NN, G_]

    // zero only the atomically-accumulated likelihood region (capture-safe)
    hipMemsetAsync(out, 0, (size_t)NG * G_ * sizeof(float), stream);
    k_fused<<<(NN + 1023) / 1024, 256, 0, stream>>>(B, Pi, x, batch, out, outh);
}

// Round 8
// 24.098 us; speedup vs baseline: 3.1371x; 1.0917x over previous
//
#include <hip/hip_runtime.h>

#define NN 1000000
#define NG 20000
#define C_ 10
#define M_ 50
#define G_ 8

// ---------------------------------------------------------------------------
// Single fused kernel, single-writer (no atomics, no memset).
// Per block of 1024 nodes:
//  A: detect int width | stage Pi | stage B (coalesced f4)
//  B: sZB/sZP log-sum-exp (no max-sub: |B|,|Pi|<=~10 -> exp<=e^10, safe)
//     || stage x/batch -> LDS (t>=128, latency overlap)
//  C: lik+hst tables (400 entries; s_c=(logB-sZB)+(logPi-sZP); lik=sum
//     softmax(s)*s, hst=argmax_c s, strict > = first max like jnp.argmax)
//     + segment-head detection (batch sorted -> contiguous segments)
//  D1: coalesced h_states float4 stores
//  D2: one wave per owned segment: ballot-scan end (continues into global
//      batch past the block edge), gather lik[x[n]] (LDS locally, global for
//      the straddle tail), 3-shuffle reduce, PLAIN store. Gap/tail empty
//      graphs zeroed by the uniquely-owning adjacent head. Every out element
//      written exactly once -> bit-deterministic.
// ---------------------------------------------------------------------------
__global__ __launch_bounds__(256) void k_fused(const float* __restrict__ B,
                                               const float* __restrict__ Pi,
                                               const int* __restrict__ x,
                                               const int* __restrict__ batch,
                                               float* __restrict__ out,
                                               float* __restrict__ outh) {
    __shared__ float sB[C_ * M_ * G_];   // 4000 f32
    __shared__ float sPi[C_ * G_];
    __shared__ float sZB[C_ * G_];       // log sum exp over M per (c,g)
    __shared__ float sZP[G_];            // log sum exp over C per g
    __shared__ float lik[M_ * 9];        // stride 9: gcd(9,32)=1, ~2-way conflicts
    __shared__ float hst[M_ * 9];
    __shared__ int   sx[1024];
    __shared__ int   sb[1025];           // sb[0] = batch[base-1] or -1
    __shared__ int   heads[1024];        // local start index of each owned segment
    __shared__ int   hcnt;
    __shared__ int   s_is64;

    const int t = threadIdx.x;
    const int base = blockIdx.x * 1024;
    const int limit = (NN - base < 1024) ? (NN - base) : 1024;  // multiple of 4

    // ---- phase A
    if (t < 64) {
        // x in [0,50): if int64, every odd int32 word is zero. P_false = 50^-128.
        const int v = x[2 * t + 1] | x[128 + 2 * t + 1];
        const unsigned long long nz = __ballot(v != 0);
        if (t == 0) { s_is64 = (nz == 0ULL) ? 1 : 0; hcnt = 0; }
    } else if (t < 144) {
        sPi[t - 64] = Pi[t - 64];
    }
    for (int i = t; i < C_ * M_ * G_ / 4; i += 256)
        ((float4*)sB)[i] = ((const float4*)B)[i];
    __syncthreads();
    const int is64 = s_is64;

    // ---- phase B: log-sum-exps || x/batch staging
    if (t < 80) {
        const int c = t >> 3, g = t & 7;
        float Z = 0.f;
        for (int m = 0; m < M_; ++m) Z += __expf(sB[(c * M_ + m) * G_ + g]);
        sZB[t] = __logf(Z);
    } else if (t < 88) {
        const int g = t - 80;
        float Z = 0.f;
        for (int c = 0; c < C_; ++c) Z += __expf(sPi[c * G_ + g]);
        sZP[g] = __logf(Z);
    } else if (t >= 128) {
        if (is64) {
            const int4* xq = (const int4*)x + (base >> 1);      // 2 int64 per int4
            const int4* bq = (const int4*)batch + (base >> 1);
            for (int i = t - 128; i < (limit >> 1); i += 128) {
                const int4 v = xq[i];
                sx[2 * i] = v.x; sx[2 * i + 1] = v.z;
                const int4 w = bq[i];
                sb[1 + 2 * i] = w.x; sb[2 + 2 * i] = w.z;
            }
            if (t == 128) sb[0] = (base == 0) ? -1 : batch[2 * (base - 1)];
        } else {
            const int4* xq = (const int4*)x + (base >> 2);
            const int4* bq = (const int4*)batch + (base >> 2);
            for (int i = t - 128; i < (limit >> 2); i += 128) {
                const int4 v = xq[i];
                sx[4 * i] = v.x; sx[4 * i + 1] = v.y; sx[4 * i + 2] = v.z; sx[4 * i + 3] = v.w;
                const int4 w = bq[i];
                sb[1 + 4 * i] = w.x; sb[2 + 4 * i] = w.y; sb[3 + 4 * i] = w.z; sb[4 + 4 * i] = w.w;
            }
            if (t == 128) sb[0] = (base == 0) ? -1 : batch[base - 1];
        }
    }
    __syncthreads();

    // ---- phase C: tables + owned-segment heads
    for (int e = t; e < M_ * G_; e += 256) {
        const int m = e >> 3, g = e & 7;
        float s[C_];
        float bv = -1e30f;
        int bi = 0;
        for (int c = 0; c < C_; ++c) {
            const float v = (sB[(c * M_ + m) * G_ + g] - sZB[c * G_ + g]) +
                            (sPi[c * G_ + g] - sZP[g]);
            s[c] = v;
            if (v > bv) { bv = v; bi = c; }  // strict > keeps FIRST max
        }
        float Z = 0.f, W = 0.f;
        for (int c = 0; c < C_; ++c) {
            const float ee = __expf(s[c]);   // s in [-32,0]: no under/overflow
            Z += ee;
            W += ee * s[c];
        }
        lik[m * 9 + g] = W / Z;
        hst[m * 9 + g] = (float)bi;
    }
    if (4 * t < limit) {
#pragma unroll
        for (int k = 0; k < 4; ++k) {
            const int i = 4 * t + k;
            // head iff batch changes (incl. vs prev block's last node)
            if (sb[1 + i] != sb[i])
                heads[atomicAdd(&hcnt, 1)] = i;
        }
    }
    __syncthreads();

    // ---- phase D1: h_states, fully coalesced float4 stores
    float4* op = (float4*)outh + (size_t)base * 2;
    const int nf4 = limit * 2;
    for (int idx = t; idx < nf4; idx += 256) {
        const int xi = sx[idx >> 1];
        const int o = xi * 9 + (idx & 1) * 4;
        float4 v;
        v.x = hst[o]; v.y = hst[o + 1]; v.z = hst[o + 2]; v.w = hst[o + 3];
        op[idx] = v;
    }

    // ---- phase D2: owned segments -> plain stores
    const int wid = t >> 6, lane = t & 63;
    const int ns = lane >> 3, r = lane & 7;
    const int H = hcnt;
    for (int j = wid; j < H; j += 4) {
        const int i0 = heads[j];
        const int g  = sb[1 + i0];
        const int gp = sb[i0];
        if (lane < 8)                      // empty graphs in (gp, g): zero once
            for (int gg = gp + 1; gg < g; ++gg)
                out[(size_t)gg * 8 + lane] = 0.f;

        const int n0 = base + i0;
        // find segment end: LDS-backed locally, global batch past block edge
        int n_end = NN;
        for (int bse = n0; ; bse += 64) {
            const int ii = bse + lane;
            int val = g + 1;               // differs (also covers ii >= NN)
            if (ii < NN)
                val = (ii < base + limit) ? sb[1 + ii - base]
                                          : (is64 ? batch[2 * (size_t)ii] : batch[ii]);
            const unsigned long long diff = __ballot(val != g);
            if (diff) { n_end = bse + (int)__builtin_ctzll(diff); break; }
        }

        float acc = 0.f;
        for (int n = n0 + ns; n < n_end; n += 8) {
            const int xi = (n < base + limit) ? sx[n - base]
                                              : (is64 ? x[2 * (size_t)n] : x[n]);
            acc += lik[xi * 9 + r];
        }
        acc += __shfl_xor(acc, 8, 64);
        acc += __shfl_xor(acc, 16, 64);
        acc += __shfl_xor(acc, 32, 64);
        if (lane < 8) out[(size_t)g * 8 + lane] = acc;

        if (n_end == NN && lane < 8)       // trailing empty graphs: zero once
            for (int gg = g + 1; gg < NG; ++gg)
                out[(size_t)gg * 8 + lane] = 0.f;
    }
}

// ---------------------------------------------------------------------------
extern "C" void kernel_launch(void* const* d_in, const int* in_sizes, int n_in,
                              void* d_out, int out_size, void* d_ws, size_t ws_size,
                              hipStream_t stream) {
    const int*   x     = (const int*)d_in[0];
    const int*   batch = (const int*)d_in[1];
    const float* B     = (const float*)d_in[2];
    const float* Pi    = (const float*)d_in[3];
    float* out  = (float*)d_out;             // likelihood [NG, G_] first
    float* outh = (float*)d_out + NG * G_;   // then h_states [NN, G_]

    k_fused<<<(NN + 1023) / 1024, 256, 0, stream>>>(B, Pi, x, batch, out, outh);
}